// Round 4
// baseline (662.050 us; speedup 1.0000x reference)
//
#include <hip/hip_runtime.h>
#include <hip/hip_bf16.h>

// Shapes: B=16, C=768, HW=4096.
#define BATCH 16
#define CDIM 768
#define NDIM 4096

typedef float  floatx4 __attribute__((ext_vector_type(4)));
typedef short  bf16x8  __attribute__((ext_vector_type(8)));

__device__ __forceinline__ short f2bf(float f) {
  unsigned u = __float_as_uint(f);
  unsigned r = (u + 0x7FFFu + ((u >> 16) & 1u)) >> 16;  // RNE
  return (short)r;
}

// async global->LDS, 16B per lane. LDS dest = wave-uniform base + lane*16.
__device__ __forceinline__ void gl_lds16(const short* g, short* l) {
  __builtin_amdgcn_global_load_lds(
      (const __attribute__((address_space(1))) unsigned int*)g,
      (__attribute__((address_space(3))) unsigned int*)l, 16, 0, 0);
}

// barrier with compiler memory fences: no LDS/global op moves across.
__device__ __forceinline__ void barrier_f() {
  asm volatile("" ::: "memory");
  __builtin_amdgcn_s_barrier();
  asm volatile("" ::: "memory");
}

// ---------------- kernel 1: fp32 -> bf16 elementwise ----------------
__global__ __launch_bounds__(256) void k_cvt(const float* __restrict__ x,
                                             short* __restrict__ xb) {
  size_t i = ((size_t)blockIdx.x * 256 + threadIdx.x) * 16;
  const floatx4* src = (const floatx4*)(x + i);
  floatx4 f0 = src[0], f1 = src[1], f2 = src[2], f3 = src[3];
  bf16x8 lo, hi;
#pragma unroll
  for (int j = 0; j < 4; j++) {
    lo[j]     = f2bf(f0[j]);
    lo[j + 4] = f2bf(f1[j]);
    hi[j]     = f2bf(f2[j]);
    hi[j + 4] = f2bf(f3[j]);
  }
  *(bf16x8*)(xb + i)     = lo;
  *(bf16x8*)(xb + i + 8) = hi;
}

// ---------------- kernel 2: tiled transpose fp32 -> bf16 ----------------
__global__ __launch_bounds__(256) void k_transpose(const float* __restrict__ X,
                                                   short* __restrict__ XT) {
  __shared__ __align__(16) short T[64][72];  // +8 pad
  int b = blockIdx.z;
  const float* Xb = X + (size_t)b * CDIM * NDIM;
  short* XTb = XT + (size_t)b * NDIM * CDIM;
  int r  = threadIdx.x >> 2;   // 0..63
  int cq = threadIdx.x & 3;    // 0..3 (16-col chunk)
  int gr  = blockIdx.y * 64 + r;         // c index
  int gc0 = blockIdx.x * 64 + cq * 16;   // n index base
  const floatx4* src = (const floatx4*)(Xb + (size_t)gr * NDIM + gc0);
  floatx4 f0 = src[0], f1 = src[1], f2 = src[2], f3 = src[3];
  bf16x8 lo, hi;
#pragma unroll
  for (int j = 0; j < 4; j++) {
    lo[j] = f2bf(f0[j]); lo[j + 4] = f2bf(f1[j]);
    hi[j] = f2bf(f2[j]); hi[j + 4] = f2bf(f3[j]);
  }
  *(bf16x8*)&T[r][cq * 16]     = lo;
  *(bf16x8*)&T[r][cq * 16 + 8] = hi;
  __syncthreads();
  bf16x8 o0, o1;
#pragma unroll
  for (int j = 0; j < 8; j++) o0[j] = T[cq * 16 + j][r];
#pragma unroll
  for (int j = 0; j < 8; j++) o1[j] = T[cq * 16 + 8 + j][r];
  short* dst = XTb + (size_t)(blockIdx.x * 64 + r) * CDIM + blockIdx.y * 64 + cq * 16;
  *(bf16x8*)dst       = o0;
  *(bf16x8*)(dst + 8) = o1;
}

// ---------------- kernel 3: bt-GEMM, 256x256 tile, 8 waves, 8-phase -------
// C[m][n] = scale * sum_k A[m][k] * Bt[n][k]   (per batch)
//
// R3 post-mortem: 573 TF = the documented 2-phase ceiling (m233); tile time
// ~5100 cyc vs ~620 cyc MFMA/SIMD + ~1300 cyc LDS -> schedule-bound, plus
// 7.08M bank-conflict cycles (each 8-lane group of a b128 read hit one
// 4-bank quad). This round ports the m201 combo onto the SAME skeleton:
//  T3: each K-tile = 4 phases {ds_reads -> barrier -> setprio(1) -> 16 MFMA
//      -> setprio(0) -> barrier}. Buffer validity still per-tile (vmcnt(8)
//      ledger from R1/R3, unchanged) -> no new race surface.
//  T2: chunk-XOR swizzle, both-sides-or-neither (rule #21): LDS dest linear,
//      DMA *source* chunk = lc ^ lr, read chunk = (ks*4+quad) ^ (row&7).
//      Every consecutive-8-lane group then covers all 32 banks exactly once
//      -> b128 at the 8-cycle floor.
//  T5: setprio around each MFMA cluster (pays only with the phase split).
// Geometry (256^2, 8 waves, 128x64/wave, BK=64, GS=544 groups) identical to
// m201's verified template and to R3.
template <int M, int N, int K, int TM, int TN, bool SCALE>
__global__ __launch_bounds__(512, 2) void k_gemm(const short* __restrict__ A,
                                                 const short* __restrict__ Bt,
                                                 float* __restrict__ C,
                                                 const float* __restrict__ gamma) {
  constexpr int GS = 544;   // shorts per 8-row group (1024 B + 64 B pad)
  constexpr int PB = TM * TN;
  constexpr int NT = K / 64;          // >= 12 for both instantiations
  __shared__ __align__(16) short Al[2][32 * GS];   // 256 rows x 64 K, dbuf
  __shared__ __align__(16) short Bl[2][32 * GS];

  int xcd = blockIdx.x;                 // 0..7
  int y   = blockIdx.y;                 // 0..2*PB-1
  int b   = xcd + 8 * (y / PB);         // batch pinned to this XCD
  int r   = y % PB;
  int tm  = r % TM;
  int tn  = r / TM;

  const short* Ab = A  + (size_t)b * M * K;
  const short* Bb = Bt + (size_t)b * N * K;
  float* Cb = C + (size_t)b * M * N;

  int tid  = threadIdx.x;
  int lane = tid & 63;
  int wave = tid >> 6;                  // 0..7
  int wm = (wave >> 2) * 128;           // wave tile: 128 (m) x 64 (n)
  int wn = (wave & 3) * 64;

  // DMA: wave covers rows [wave*32, +32) = groups [wave*4, +4), 4 issues
  // per operand per K-tile. Source chunk pre-swizzled (lc ^ lr) so the
  // LINEAR LDS dest receives the swizzled layout (rule #21 / m173).
  int lr = lane >> 3;    // row within 8-row issue (0..7)
  int lc = lane & 7;     // 16B chunk within row
  int swzc = lc ^ lr;    // swizzled source chunk
  const short* ga = Ab + (size_t)(tm * 256 + wave * 32 + lr) * K + swzc * 8;
  const short* gb = Bb + (size_t)(tn * 256 + wave * 32 + lr) * K + swzc * 8;
  int lofs = wave * 4 * GS;

  // stage one 64-wide K-tile into buffer `buf`; advances ga/gb by 64.
  auto stage = [&](int buf) {
#pragma unroll
    for (int j = 0; j < 4; j++)
      gl_lds16(ga + (size_t)j * 8 * K, &Al[buf][lofs + j * GS]);
#pragma unroll
    for (int j = 0; j < 4; j++)
      gl_lds16(gb + (size_t)j * 8 * K, &Bl[buf][lofs + j * GS]);
    ga += 64; gb += 64;
  };

  floatx4 acc[8][4] = {};
  int row = lane & 15, quad = lane >> 4;
  int x0 = row & 7;

  // fragment read bases (shorts): group base + row-within-group.
  // LDS(group g, row r7, chunk x) holds global chunk (x ^ r7) of row 8g+r7,
  // so reading global chunk cc uses chunk field cc ^ r7.
  int ra[8], rb[4];
#pragma unroll
  for (int i = 0; i < 8; i++) ra[i] = (((wm + i * 16 + row) >> 3) * GS) + x0 * 64;
#pragma unroll
  for (int j = 0; j < 4; j++) rb[j] = (((wn + j * 16 + row) >> 3) * GS) + x0 * 64;

  stage(0);   // tile 0 -> buf0
  stage(1);   // tile 1 -> buf1   (16 loads outstanding per wave)

  for (int t = 0; t < NT; ++t) {
    int buf = t & 1;
    // Wait for OWN tile-t loads (oldest 8). Tile t+1's 8 stay in flight,
    // except on the last iteration where nothing is behind -> vmcnt(0).
    if (t == NT - 1) asm volatile("s_waitcnt vmcnt(0)" ::: "memory");
    else             asm volatile("s_waitcnt vmcnt(8)" ::: "memory");
    barrier_f();                         // ALL waves' tile-t loads landed

    const short* Ap = Al[buf];
    const short* Bp = Bl[buf];
    bf16x8 af[8], bfv[4];

#pragma unroll
    for (int ks = 0; ks < 2; ks++) {
      int cs = ((ks * 4 + quad) ^ x0) * 8;   // swizzled chunk offset (shorts)

      // ---- phase 2*ks+0: read af[0..3] + bfv[0..3]; MFMA i=0..3 ----
#pragma unroll
      for (int i = 0; i < 4; i++) af[i] = *(const bf16x8*)&Ap[ra[i] + cs];
#pragma unroll
      for (int j = 0; j < 4; j++) bfv[j] = *(const bf16x8*)&Bp[rb[j] + cs];
      barrier_f();
      __builtin_amdgcn_s_setprio(1);
#pragma unroll
      for (int i = 0; i < 4; i++)
#pragma unroll
        for (int j = 0; j < 4; j++)
          acc[i][j] = __builtin_amdgcn_mfma_f32_16x16x32_bf16(af[i], bfv[j], acc[i][j], 0, 0, 0);
      __builtin_amdgcn_s_setprio(0);
      barrier_f();

      // ---- phase 2*ks+1: read af[4..7]; MFMA i=4..7 (bfv reused) ----
#pragma unroll
      for (int i = 4; i < 8; i++) af[i] = *(const bf16x8*)&Ap[ra[i] + cs];
      barrier_f();
      __builtin_amdgcn_s_setprio(1);
#pragma unroll
      for (int i = 4; i < 8; i++)
#pragma unroll
        for (int j = 0; j < 4; j++)
          acc[i][j] = __builtin_amdgcn_mfma_f32_16x16x32_bf16(af[i], bfv[j], acc[i][j], 0, 0, 0);
      __builtin_amdgcn_s_setprio(0);
      if (ks == 1)  // insurance: all LDS reads retired before buf overwrite
        asm volatile("s_waitcnt lgkmcnt(0)" ::: "memory");
      barrier_f();
    }

    if (t + 2 < NT) stage(buf);          // tile t+2 overwrites buf[t&1]
  }

  float g = SCALE ? gamma[0] : 1.0f;
  int col = lane & 15, rq = (lane >> 4) * 4;  // C/D: col=lane&15, row=quad*4+reg
#pragma unroll
  for (int i = 0; i < 8; i++)
#pragma unroll
    for (int j = 0; j < 4; j++)
#pragma unroll
      for (int rr = 0; rr < 4; rr++) {
        int m = tm * 256 + wm + i * 16 + rq + rr;
        int n = tn * 256 + wn + j * 16 + col;
        Cb[(size_t)m * N + n] = g * acc[i][j][rr];
      }
}

// ---------------- kernel 4: row softmax fp32 -> bf16 ----------------
__global__ __launch_bounds__(256) void k_softmax(const float* __restrict__ S,
                                                 short* __restrict__ P) {
  size_t row = blockIdx.x;
  const float* s = S + row * CDIM;
  short* p = P + row * CDIM;
  int tid = threadIdx.x;
  float v0 = s[tid], v1 = s[tid + 256], v2 = s[tid + 512];
  float m = fmaxf(fmaxf(v0, v1), v2);
#pragma unroll
  for (int o = 32; o; o >>= 1) m = fmaxf(m, __shfl_xor(m, o, 64));
  __shared__ float rmax[4], rsum[4];
  if ((tid & 63) == 0) rmax[tid >> 6] = m;
  __syncthreads();
  m = fmaxf(fmaxf(rmax[0], rmax[1]), fmaxf(rmax[2], rmax[3]));
  float e0 = __expf(v0 - m), e1 = __expf(v1 - m), e2 = __expf(v2 - m);
  float su = e0 + e1 + e2;
#pragma unroll
  for (int o = 32; o; o >>= 1) su += __shfl_xor(su, o, 64);
  if ((tid & 63) == 0) rsum[tid >> 6] = su;
  __syncthreads();
  float inv = 1.0f / (rsum[0] + rsum[1] + rsum[2] + rsum[3]);
  p[tid]       = f2bf(e0 * inv);
  p[tid + 256] = f2bf(e1 * inv);
  p[tid + 512] = f2bf(e2 * inv);
}

extern "C" void kernel_launch(void* const* d_in, const int* in_sizes, int n_in,
                              void* d_out, int out_size, void* d_ws, size_t ws_size,
                              hipStream_t stream) {
  const float* x     = (const float*)d_in[0];
  const float* gamma = (const float*)d_in[1];
  float* out = (float*)d_out;

  // workspace layout (150 MiB), proven in R1/R3/R4:
  //   [0, 100663296)         : Xb bf16 (phase 1) / XT bf16 (phase 2)
  //   [100663296, +37748736) : S fp32 [16][768][768]
  //   [+, +18874368)         : P bf16 [16][768][768]
  char* ws = (char*)d_ws;
  short* Xb = (short*)ws;
  float* S  = (float*)(ws + 100663296);
  short* P  = (short*)(ws + 100663296 + 37748736);

  // 1) X -> bf16 (row-major)
  {
    size_t total = (size_t)BATCH * CDIM * NDIM;  // 50331648
    k_cvt<<<(int)(total / (256 * 16)), 256, 0, stream>>>(x, Xb);
  }
  // 2) S = Xb * Xb^T  (M=N=768, K=4096), 256^2 tiles: 8 x 18 blocks
  k_gemm<CDIM, CDIM, NDIM, 3, 3, false>
      <<<dim3(8, 2 * 3 * 3, 1), 512, 0, stream>>>(Xb, Xb, S, nullptr);
  // 3) P = softmax_rows(S), bf16
  k_softmax<<<BATCH * CDIM, 256, 0, stream>>>(S, P);
  // 4) XT = transpose(X) in bf16 (overwrites Xb region; Xb dead after step 2)
  k_transpose<<<dim3(NDIM / 64, CDIM / 64, BATCH), 256, 0, stream>>>(x, Xb);
  // 5) out = gamma * (P * XT^T)  (M=768, N=4096, K=768), 256^2 tiles: 8 x 96
  k_gemm<CDIM, NDIM, CDIM, 3, 16, true>
      <<<dim3(8, 2 * 3 * 16, 1), 512, 0, stream>>>(P, Xb, out, gamma);
}

// Round 5
// 598.739 us; speedup vs baseline: 1.1057x; 1.1057x over previous
//
#include <hip/hip_runtime.h>
#include <hip/hip_bf16.h>

// Shapes: B=16, C=768, HW=4096.
#define BATCH 16
#define CDIM 768
#define NDIM 4096

typedef float  floatx4 __attribute__((ext_vector_type(4)));
typedef short  bf16x8  __attribute__((ext_vector_type(8)));

__device__ __forceinline__ short f2bf(float f) {
  unsigned u = __float_as_uint(f);
  unsigned r = (u + 0x7FFFu + ((u >> 16) & 1u)) >> 16;  // RNE
  return (short)r;
}

// async global->LDS, 16B per lane. LDS dest = wave-uniform base + lane*16.
__device__ __forceinline__ void gl_lds16(const short* g, short* l) {
  __builtin_amdgcn_global_load_lds(
      (const __attribute__((address_space(1))) unsigned int*)g,
      (__attribute__((address_space(3))) unsigned int*)l, 16, 0, 0);
}

// ---------------- kernel 1: fp32 -> bf16 elementwise ----------------
__global__ __launch_bounds__(256) void k_cvt(const float* __restrict__ x,
                                             short* __restrict__ xb) {
  size_t i = ((size_t)blockIdx.x * 256 + threadIdx.x) * 16;
  const floatx4* src = (const floatx4*)(x + i);
  floatx4 f0 = src[0], f1 = src[1], f2 = src[2], f3 = src[3];
  bf16x8 lo, hi;
#pragma unroll
  for (int j = 0; j < 4; j++) {
    lo[j]     = f2bf(f0[j]);
    lo[j + 4] = f2bf(f1[j]);
    hi[j]     = f2bf(f2[j]);
    hi[j + 4] = f2bf(f3[j]);
  }
  *(bf16x8*)(xb + i)     = lo;
  *(bf16x8*)(xb + i + 8) = hi;
}

// ---------------- kernel 2: tiled transpose fp32 -> bf16 ----------------
__global__ __launch_bounds__(256) void k_transpose(const float* __restrict__ X,
                                                   short* __restrict__ XT) {
  __shared__ __align__(16) short T[64][72];  // +8 pad
  int b = blockIdx.z;
  const float* Xb = X + (size_t)b * CDIM * NDIM;
  short* XTb = XT + (size_t)b * NDIM * CDIM;
  int r  = threadIdx.x >> 2;   // 0..63
  int cq = threadIdx.x & 3;    // 0..3 (16-col chunk)
  int gr  = blockIdx.y * 64 + r;         // c index
  int gc0 = blockIdx.x * 64 + cq * 16;   // n index base
  const floatx4* src = (const floatx4*)(Xb + (size_t)gr * NDIM + gc0);
  floatx4 f0 = src[0], f1 = src[1], f2 = src[2], f3 = src[3];
  bf16x8 lo, hi;
#pragma unroll
  for (int j = 0; j < 4; j++) {
    lo[j] = f2bf(f0[j]); lo[j + 4] = f2bf(f1[j]);
    hi[j] = f2bf(f2[j]); hi[j + 4] = f2bf(f3[j]);
  }
  *(bf16x8*)&T[r][cq * 16]     = lo;
  *(bf16x8*)&T[r][cq * 16 + 8] = hi;
  __syncthreads();
  bf16x8 o0, o1;
#pragma unroll
  for (int j = 0; j < 8; j++) o0[j] = T[cq * 16 + j][r];
#pragma unroll
  for (int j = 0; j < 8; j++) o1[j] = T[cq * 16 + 8 + j][r];
  short* dst = XTb + (size_t)(blockIdx.x * 64 + r) * CDIM + blockIdx.y * 64 + cq * 16;
  *(bf16x8*)dst       = o0;
  *(bf16x8*)(dst + 8) = o1;
}

// ---------------- kernel 3: bt-GEMM, (BM x BN) tile, 8 waves, 2-phase -----
// C[m][n] = scale * sum_k A[m][k] * Bt[n][k]   (per batch)
//
// R4 post-mortem: (a) SQ_LDS_BANK_CONFLICT decomposes EXACTLY as 4 counted
// cycles per ds_read_b128 in every round/layout -> it's the structural b128
// port floor (1024 B/instr > 256 B/clk), NOT a fixable conflict. Layout
// stays as-is. (b) Coarse phase-split (6 barriers/tile, no staged interleave)
// regressed 136->170 us, confirming m196: phase barriers without the full
// m201 stagger are pure overhead. -> inner loop reverted to R3-exact
// 2-phase counted-vmcnt pipeline (best measured).
//
// ONE variable this round: GEMM1 grid fill. R3 ran GEMM1 as 144 blocks on
// 256 CUs (1 block/CU max, LDS-bound) -> 44% of CUs idle. Template now
// takes (BM, BN): GEMM1 uses 192x192 -> (768/192)^2*16 = 256 blocks =
// perfect 1/CU fill; GEMM2 keeps 256x256 (768 blocks = 3 even rounds).
// All constants derived compile-time; structure identical to R3.
template <int M, int N, int K, int BM, int BN, bool SCALE>
__global__ __launch_bounds__(512, 2) void k_gemm(const short* __restrict__ A,
                                                 const short* __restrict__ Bt,
                                                 float* __restrict__ C,
                                                 const float* __restrict__ gamma) {
  constexpr int GS  = 544;      // shorts per 8-row group (1024 B + 64 B pad)
  constexpr int GA  = BM / 8;   // A groups per tile
  constexpr int GB  = BN / 8;   // B groups per tile
  constexpr int IA  = BM / 64;  // DMA issues per wave per tile (A)
  constexpr int IB  = BN / 64;  // DMA issues per wave per tile (B)
  constexpr int IPT = IA + IB;  // per-wave vmcnt ledger per tile
  constexpr int WM  = BM / 2;   // wave tile m (2 wave rows)
  constexpr int WN  = BN / 4;   // wave tile n (4 wave cols)
  constexpr int MF  = WM / 16;  // m fragments per wave
  constexpr int NF  = WN / 16;  // n fragments per wave
  constexpr int TMC = M / BM;
  constexpr int PB  = TMC * (N / BN);
  constexpr int NT  = K / 64;
  __shared__ __align__(16) short Al[2][GA * GS];
  __shared__ __align__(16) short Bl[2][GB * GS];

  int xcd = blockIdx.x;                 // 0..7
  int y   = blockIdx.y;                 // 0..2*PB-1
  int b   = xcd + 8 * (y / PB);         // batch pinned to this XCD
  int r   = y % PB;
  int tm  = r % TMC;
  int tn  = r / TMC;

  const short* Ab = A  + (size_t)b * M * K;
  const short* Bb = Bt + (size_t)b * N * K;
  float* Cb = C + (size_t)b * M * N;

  int tid  = threadIdx.x;
  int lane = tid & 63;
  int wave = tid >> 6;                  // 0..7
  int wm = (wave >> 2) * WM;            // wave tile: WM (m) x WN (n)
  int wn = (wave & 3) * WN;

  // DMA: wave covers A rows [wave*IA*8, +IA*8) = groups [wave*IA, +IA).
  int lr = lane >> 3;    // row within 8-row issue
  int lc = lane & 7;     // 16B chunk within row
  const short* ga = Ab + (size_t)(tm * BM + wave * IA * 8 + lr) * K + lc * 8;
  const short* gb = Bb + (size_t)(tn * BN + wave * IB * 8 + lr) * K + lc * 8;
  int lofs_a = wave * IA * GS;
  int lofs_b = wave * IB * GS;

  // stage one 64-wide K-tile into buffer `buf`; advances ga/gb by 64.
  auto stage = [&](int buf) {
#pragma unroll
    for (int j = 0; j < IA; j++)
      gl_lds16(ga + (size_t)j * 8 * K, &Al[buf][lofs_a + j * GS]);
#pragma unroll
    for (int j = 0; j < IB; j++)
      gl_lds16(gb + (size_t)j * 8 * K, &Bl[buf][lofs_b + j * GS]);
    ga += 64; gb += 64;
  };

  floatx4 acc[MF][NF] = {};
  int row = lane & 15, quad = lane >> 4;

  stage(0);   // tile 0 -> buf0
  stage(1);   // tile 1 -> buf1   (2*IPT loads outstanding per wave)

  for (int t = 0; t < NT; ++t) {
    int buf = t & 1;
    // Wait for OWN tile-t loads (oldest IPT). Tile t+1's IPT stay in
    // flight, except the last iteration (nothing behind) -> vmcnt(0).
    if (t == NT - 1) {
      asm volatile("s_waitcnt vmcnt(0)" ::: "memory");
    } else if constexpr (IPT == 6) {
      asm volatile("s_waitcnt vmcnt(6)" ::: "memory");
    } else {
      asm volatile("s_waitcnt vmcnt(8)" ::: "memory");
    }
    __builtin_amdgcn_s_barrier();        // ALL waves' tile-t loads landed
    asm volatile("" ::: "memory");       // no ds_read hoisted above barrier

#pragma unroll
    for (int ks = 0; ks < 2; ks++) {
      bf16x8 af[MF], bfv[NF];
#pragma unroll
      for (int i = 0; i < MF; i++) {
        int R = wm + i * 16 + row;
        af[i] = *(const bf16x8*)&Al[buf][(R >> 3) * GS + (R & 7) * 64 + (ks * 4 + quad) * 8];
      }
#pragma unroll
      for (int j = 0; j < NF; j++) {
        int R = wn + j * 16 + row;
        bfv[j] = *(const bf16x8*)&Bl[buf][(R >> 3) * GS + (R & 7) * 64 + (ks * 4 + quad) * 8];
      }
#pragma unroll
      for (int i = 0; i < MF; i++)
#pragma unroll
        for (int j = 0; j < NF; j++)
          acc[i][j] = __builtin_amdgcn_mfma_f32_16x16x32_bf16(af[i], bfv[j], acc[i][j], 0, 0, 0);
    }

    asm volatile("" ::: "memory");       // no memory op crosses downward
    __builtin_amdgcn_s_barrier();        // all waves done reading buf[t&1]
    asm volatile("" ::: "memory");       // stage not hoisted above barrier
    if (t + 2 < NT) stage(buf);          // tile t+2 overwrites buf[t&1]
  }

  float g = SCALE ? gamma[0] : 1.0f;
  int col = lane & 15, rq = (lane >> 4) * 4;  // C/D: col=lane&15, row=quad*4+reg
#pragma unroll
  for (int i = 0; i < MF; i++)
#pragma unroll
    for (int j = 0; j < NF; j++)
#pragma unroll
      for (int rr = 0; rr < 4; rr++) {
        int m = tm * BM + wm + i * 16 + rq + rr;
        int n = tn * BN + wn + j * 16 + col;
        Cb[(size_t)m * N + n] = g * acc[i][j][rr];
      }
}

// ---------------- kernel 4: row softmax fp32 -> bf16 ----------------
__global__ __launch_bounds__(256) void k_softmax(const float* __restrict__ S,
                                                 short* __restrict__ P) {
  size_t row = blockIdx.x;
  const float* s = S + row * CDIM;
  short* p = P + row * CDIM;
  int tid = threadIdx.x;
  float v0 = s[tid], v1 = s[tid + 256], v2 = s[tid + 512];
  float m = fmaxf(fmaxf(v0, v1), v2);
#pragma unroll
  for (int o = 32; o; o >>= 1) m = fmaxf(m, __shfl_xor(m, o, 64));
  __shared__ float rmax[4], rsum[4];
  if ((tid & 63) == 0) rmax[tid >> 6] = m;
  __syncthreads();
  m = fmaxf(fmaxf(rmax[0], rmax[1]), fmaxf(rmax[2], rmax[3]));
  float e0 = __expf(v0 - m), e1 = __expf(v1 - m), e2 = __expf(v2 - m);
  float su = e0 + e1 + e2;
#pragma unroll
  for (int o = 32; o; o >>= 1) su += __shfl_xor(su, o, 64);
  if ((tid & 63) == 0) rsum[tid >> 6] = su;
  __syncthreads();
  float inv = 1.0f / (rsum[0] + rsum[1] + rsum[2] + rsum[3]);
  p[tid]       = f2bf(e0 * inv);
  p[tid + 256] = f2bf(e1 * inv);
  p[tid + 512] = f2bf(e2 * inv);
}

extern "C" void kernel_launch(void* const* d_in, const int* in_sizes, int n_in,
                              void* d_out, int out_size, void* d_ws, size_t ws_size,
                              hipStream_t stream) {
  const float* x     = (const float*)d_in[0];
  const float* gamma = (const float*)d_in[1];
  float* out = (float*)d_out;

  // workspace layout (150 MiB), proven in R1/R3/R4:
  //   [0, 100663296)         : Xb bf16 (phase 1) / XT bf16 (phase 2)
  //   [100663296, +37748736) : S fp32 [16][768][768]
  //   [+, +18874368)         : P bf16 [16][768][768]
  char* ws = (char*)d_ws;
  short* Xb = (short*)ws;
  float* S  = (float*)(ws + 100663296);
  short* P  = (short*)(ws + 100663296 + 37748736);

  // 1) X -> bf16 (row-major)
  {
    size_t total = (size_t)BATCH * CDIM * NDIM;  // 50331648
    k_cvt<<<(int)(total / (256 * 16)), 256, 0, stream>>>(x, Xb);
  }
  // 2) S = Xb * Xb^T  (M=N=768, K=4096), 192^2 tiles: 8 x 32 = 256 blocks
  //    = exactly 1 block/CU (R3's 256^2 left 112 CUs idle).
  k_gemm<CDIM, CDIM, NDIM, 192, 192, false>
      <<<dim3(8, 2 * 16, 1), 512, 0, stream>>>(Xb, Xb, S, nullptr);
  // 3) P = softmax_rows(S), bf16
  k_softmax<<<BATCH * CDIM, 256, 0, stream>>>(S, P);
  // 4) XT = transpose(X) in bf16 (overwrites Xb region; Xb dead after step 2)
  k_transpose<<<dim3(NDIM / 64, CDIM / 64, BATCH), 256, 0, stream>>>(x, Xb);
  // 5) out = gamma * (P * XT^T)  (M=768, N=4096, K=768), 256^2: 8 x 96 = 768
  k_gemm<CDIM, NDIM, CDIM, 256, 256, true>
      <<<dim3(8, 2 * 48, 1), 512, 0, stream>>>(P, Xb, out, gamma);
}

// Round 6
// 579.478 us; speedup vs baseline: 1.1425x; 1.0332x over previous
//
#include <hip/hip_runtime.h>
#include <hip/hip_bf16.h>

// Shapes: B=16, C=768, HW=4096.
#define BATCH 16
#define CDIM 768
#define NDIM 4096

typedef float  floatx4 __attribute__((ext_vector_type(4)));
typedef short  bf16x8  __attribute__((ext_vector_type(8)));

__device__ __forceinline__ short f2bf(float f) {
  unsigned u = __float_as_uint(f);
  unsigned r = (u + 0x7FFFu + ((u >> 16) & 1u)) >> 16;  // RNE
  return (short)r;
}

// async global->LDS, 16B per lane. LDS dest = wave-uniform base + lane*16.
__device__ __forceinline__ void gl_lds16(const short* g, short* l) {
  __builtin_amdgcn_global_load_lds(
      (const __attribute__((address_space(1))) unsigned int*)g,
      (__attribute__((address_space(3))) unsigned int*)l, 16, 0, 0);
}

// barrier with compiler memory fences: no LDS/global op moves across.
__device__ __forceinline__ void barrier_f() {
  asm volatile("" ::: "memory");
  __builtin_amdgcn_s_barrier();
  asm volatile("" ::: "memory");
}

// ---------------- kernel 1: fused cvt + transpose --------------------------
// R5 found ws_size = 768 MiB (poison fill writes exactly 768 MiB), so XT no
// longer shares the Xb buffer -> cvt and transpose fuse: read x ONCE, write
// both row-major bf16 (Xb) and transposed bf16 (XT). 402 MB HBM vs 603 MB
// for the old k_cvt + k_transpose pair.
__global__ __launch_bounds__(256) void k_prep(const float* __restrict__ X,
                                              short* __restrict__ Xb,
                                              short* __restrict__ XT) {
  __shared__ __align__(16) short T[64][72];  // +8 pad
  int b = blockIdx.z;
  const float* Xf = X + (size_t)b * CDIM * NDIM;
  short* Xrm = Xb + (size_t)b * CDIM * NDIM;
  short* Xtr = XT + (size_t)b * NDIM * CDIM;
  int r  = threadIdx.x >> 2;   // 0..63
  int cq = threadIdx.x & 3;    // 0..3 (16-col chunk)
  int gr  = blockIdx.y * 64 + r;         // c index
  int gc0 = blockIdx.x * 64 + cq * 16;   // n index base
  const floatx4* src = (const floatx4*)(Xf + (size_t)gr * NDIM + gc0);
  floatx4 f0 = src[0], f1 = src[1], f2 = src[2], f3 = src[3];
  bf16x8 lo, hi;
#pragma unroll
  for (int j = 0; j < 4; j++) {
    lo[j] = f2bf(f0[j]); lo[j + 4] = f2bf(f1[j]);
    hi[j] = f2bf(f2[j]); hi[j + 4] = f2bf(f3[j]);
  }
  // row-major bf16 out (was k_cvt)
  short* drm = Xrm + (size_t)gr * NDIM + gc0;
  *(bf16x8*)drm       = lo;
  *(bf16x8*)(drm + 8) = hi;
  // transposed bf16 out via LDS (was k_transpose)
  *(bf16x8*)&T[r][cq * 16]     = lo;
  *(bf16x8*)&T[r][cq * 16 + 8] = hi;
  __syncthreads();
  bf16x8 o0, o1;
#pragma unroll
  for (int j = 0; j < 8; j++) o0[j] = T[cq * 16 + j][r];
#pragma unroll
  for (int j = 0; j < 8; j++) o1[j] = T[cq * 16 + 8 + j][r];
  short* dst = Xtr + (size_t)(blockIdx.x * 64 + r) * CDIM + blockIdx.y * 64 + cq * 16;
  *(bf16x8*)dst       = o0;
  *(bf16x8*)(dst + 8) = o1;
}

// ---------------- kernel 3a: GEMM1, 192^2 tile, 3-slot LDS, 1 barrier/tile -
// S[m][n] = sum_k A[m][k] * A'[n][k]  (per batch), M=N=768, K=4096.
//
// R5 post-mortem: both GEMMs sit at ~650 TF = the 2-phase ceiling (m230/
// m233); the cost is the lockstep {vmcnt -> barrier -> reads -> MFMA ->
// barrier} structure, not LDS/MFMA ports. This variant (fits LDS only at
// 192^2): THREE K-tile slots. Tile t+2's DMA targets slot (t+2)%3 = tile
// t-1's slot, whose reads all completed before tile t's head barrier (a
// wave reaches it only after its t-1 MFMAs consumed every ds_read). So:
// one barrier per tile, and staging issues a full compute phase earlier
// (~2-tile lead >> HBM latency). Ledger: at head of tile t, outstanding =
// own tile t (6) + tile t+1 (6) -> vmcnt(6); vmcnt(0) at t=NT-1.
__global__ __launch_bounds__(512, 2) void k_gemm1(const short* __restrict__ A,
                                                  float* __restrict__ C) {
  constexpr int GS = 544;       // shorts per 8-row group (1024 B + 64 B pad)
  constexpr int BM = 192, BN = 192, M = CDIM, N = CDIM, K = NDIM;
  constexpr int IA = BM / 64, IB = BN / 64;     // 3 + 3 DMA issues/wave/tile
  constexpr int WM = BM / 2, WN = BN / 4;       // 96 x 48 per wave
  constexpr int MF = WM / 16, NF = WN / 16;     // 6 x 3 fragments
  constexpr int TMC = M / BM;                   // 4
  constexpr int PB  = TMC * (N / BN);           // 16
  constexpr int NT  = K / 64;                   // 64
  __shared__ __align__(16) short Al[3][(BM / 8) * GS];   // 3 x 26112 B
  __shared__ __align__(16) short Bl[3][(BN / 8) * GS];   // total 156672 B

  int xcd = blockIdx.x;
  int y   = blockIdx.y;
  int b   = xcd + 8 * (y / PB);
  int r   = y % PB;
  int tm  = r % TMC;
  int tn  = r / TMC;

  const short* Ab = A + (size_t)b * M * K;
  float* Cb = C + (size_t)b * M * N;

  int tid  = threadIdx.x;
  int lane = tid & 63;
  int wave = tid >> 6;
  int wm = (wave >> 2) * WM;
  int wn = (wave & 3) * WN;

  int lr = lane >> 3;
  int lc = lane & 7;
  const short* ga = Ab + (size_t)(tm * BM + wave * IA * 8 + lr) * K + lc * 8;
  const short* gb = Ab + (size_t)(tn * BN + wave * IB * 8 + lr) * K + lc * 8;
  int lofs_a = wave * IA * GS;
  int lofs_b = wave * IB * GS;

  auto stage = [&](int slot) {
#pragma unroll
    for (int j = 0; j < IA; j++)
      gl_lds16(ga + (size_t)j * 8 * K, &Al[slot][lofs_a + j * GS]);
#pragma unroll
    for (int j = 0; j < IB; j++)
      gl_lds16(gb + (size_t)j * 8 * K, &Bl[slot][lofs_b + j * GS]);
    ga += 64; gb += 64;
  };

  floatx4 acc[MF][NF] = {};
  int row = lane & 15, quad = lane >> 4;

  stage(0);            // tile 0
  stage(1);            // tile 1  (12 outstanding per wave)

  int cur = 0, nxt = 2;   // cur = slot of tile t; nxt = slot of tile t+2
  for (int t = 0; t < NT; ++t) {
    if (t == NT - 1) asm volatile("s_waitcnt vmcnt(0)" ::: "memory");
    else             asm volatile("s_waitcnt vmcnt(6)" ::: "memory");
    barrier_f();                       // tile-t data visible block-wide
    if (t + 2 < NT) stage(nxt);        // slot(t+2)=slot(t-1): readers done

    const short* Ap = Al[cur];
    const short* Bp = Bl[cur];
#pragma unroll
    for (int ks = 0; ks < 2; ks++) {
      bf16x8 af[MF], bfv[NF];
#pragma unroll
      for (int i = 0; i < MF; i++) {
        int R = wm + i * 16 + row;
        af[i] = *(const bf16x8*)&Ap[(R >> 3) * GS + (R & 7) * 64 + (ks * 4 + quad) * 8];
      }
#pragma unroll
      for (int j = 0; j < NF; j++) {
        int R = wn + j * 16 + row;
        bfv[j] = *(const bf16x8*)&Bp[(R >> 3) * GS + (R & 7) * 64 + (ks * 4 + quad) * 8];
      }
#pragma unroll
      for (int i = 0; i < MF; i++)
#pragma unroll
        for (int j = 0; j < NF; j++)
          acc[i][j] = __builtin_amdgcn_mfma_f32_16x16x32_bf16(af[i], bfv[j], acc[i][j], 0, 0, 0);
    }
    cur = (cur == 2) ? 0 : cur + 1;
    nxt = (nxt == 2) ? 0 : nxt + 1;
  }

  int col = lane & 15, rq = (lane >> 4) * 4;
#pragma unroll
  for (int i = 0; i < MF; i++)
#pragma unroll
    for (int j = 0; j < NF; j++)
#pragma unroll
      for (int rr = 0; rr < 4; rr++) {
        int m = tm * BM + wm + i * 16 + rq + rr;
        int n = tn * BN + wn + j * 16 + col;
        Cb[(size_t)m * N + n] = acc[i][j][rr];
      }
}

// ---------------- kernel 3b: bt-GEMM, (BM x BN) tile, 2-phase (R5-exact) ---
template <int M, int N, int K, int BM, int BN, bool SCALE>
__global__ __launch_bounds__(512, 2) void k_gemm(const short* __restrict__ A,
                                                 const short* __restrict__ Bt,
                                                 float* __restrict__ C,
                                                 const float* __restrict__ gamma) {
  constexpr int GS  = 544;
  constexpr int GA  = BM / 8;
  constexpr int GB  = BN / 8;
  constexpr int IA  = BM / 64;
  constexpr int IB  = BN / 64;
  constexpr int IPT = IA + IB;
  constexpr int WM  = BM / 2;
  constexpr int WN  = BN / 4;
  constexpr int MF  = WM / 16;
  constexpr int NF  = WN / 16;
  constexpr int TMC = M / BM;
  constexpr int PB  = TMC * (N / BN);
  constexpr int NT  = K / 64;
  __shared__ __align__(16) short Al[2][GA * GS];
  __shared__ __align__(16) short Bl[2][GB * GS];

  int xcd = blockIdx.x;
  int y   = blockIdx.y;
  int b   = xcd + 8 * (y / PB);
  int r   = y % PB;
  int tm  = r % TMC;
  int tn  = r / TMC;

  const short* Ab = A  + (size_t)b * M * K;
  const short* Bb = Bt + (size_t)b * N * K;
  float* Cb = C + (size_t)b * M * N;

  int tid  = threadIdx.x;
  int lane = tid & 63;
  int wave = tid >> 6;
  int wm = (wave >> 2) * WM;
  int wn = (wave & 3) * WN;

  int lr = lane >> 3;
  int lc = lane & 7;
  const short* ga = Ab + (size_t)(tm * BM + wave * IA * 8 + lr) * K + lc * 8;
  const short* gb = Bb + (size_t)(tn * BN + wave * IB * 8 + lr) * K + lc * 8;
  int lofs_a = wave * IA * GS;
  int lofs_b = wave * IB * GS;

  auto stage = [&](int buf) {
#pragma unroll
    for (int j = 0; j < IA; j++)
      gl_lds16(ga + (size_t)j * 8 * K, &Al[buf][lofs_a + j * GS]);
#pragma unroll
    for (int j = 0; j < IB; j++)
      gl_lds16(gb + (size_t)j * 8 * K, &Bl[buf][lofs_b + j * GS]);
    ga += 64; gb += 64;
  };

  floatx4 acc[MF][NF] = {};
  int row = lane & 15, quad = lane >> 4;

  stage(0);
  stage(1);

  for (int t = 0; t < NT; ++t) {
    int buf = t & 1;
    if (t == NT - 1) {
      asm volatile("s_waitcnt vmcnt(0)" ::: "memory");
    } else if constexpr (IPT == 6) {
      asm volatile("s_waitcnt vmcnt(6)" ::: "memory");
    } else {
      asm volatile("s_waitcnt vmcnt(8)" ::: "memory");
    }
    __builtin_amdgcn_s_barrier();
    asm volatile("" ::: "memory");

#pragma unroll
    for (int ks = 0; ks < 2; ks++) {
      bf16x8 af[MF], bfv[NF];
#pragma unroll
      for (int i = 0; i < MF; i++) {
        int R = wm + i * 16 + row;
        af[i] = *(const bf16x8*)&Al[buf][(R >> 3) * GS + (R & 7) * 64 + (ks * 4 + quad) * 8];
      }
#pragma unroll
      for (int j = 0; j < NF; j++) {
        int R = wn + j * 16 + row;
        bfv[j] = *(const bf16x8*)&Bl[buf][(R >> 3) * GS + (R & 7) * 64 + (ks * 4 + quad) * 8];
      }
#pragma unroll
      for (int i = 0; i < MF; i++)
#pragma unroll
        for (int j = 0; j < NF; j++)
          acc[i][j] = __builtin_amdgcn_mfma_f32_16x16x32_bf16(af[i], bfv[j], acc[i][j], 0, 0, 0);
    }

    asm volatile("" ::: "memory");
    __builtin_amdgcn_s_barrier();
    asm volatile("" ::: "memory");
    if (t + 2 < NT) stage(buf);
  }

  float g = SCALE ? gamma[0] : 1.0f;
  int col = lane & 15, rq = (lane >> 4) * 4;
#pragma unroll
  for (int i = 0; i < MF; i++)
#pragma unroll
    for (int j = 0; j < NF; j++)
#pragma unroll
      for (int rr = 0; rr < 4; rr++) {
        int m = tm * BM + wm + i * 16 + rq + rr;
        int n = tn * BN + wn + j * 16 + col;
        Cb[(size_t)m * N + n] = g * acc[i][j][rr];
      }
}

// ---------------- kernel 4: row softmax fp32 -> bf16 ----------------
__global__ __launch_bounds__(256) void k_softmax(const float* __restrict__ S,
                                                 short* __restrict__ P) {
  size_t row = blockIdx.x;
  const float* s = S + row * CDIM;
  short* p = P + row * CDIM;
  int tid = threadIdx.x;
  float v0 = s[tid], v1 = s[tid + 256], v2 = s[tid + 512];
  float m = fmaxf(fmaxf(v0, v1), v2);
#pragma unroll
  for (int o = 32; o; o >>= 1) m = fmaxf(m, __shfl_xor(m, o, 64));
  __shared__ float rmax[4], rsum[4];
  if ((tid & 63) == 0) rmax[tid >> 6] = m;
  __syncthreads();
  m = fmaxf(fmaxf(rmax[0], rmax[1]), fmaxf(rmax[2], rmax[3]));
  float e0 = __expf(v0 - m), e1 = __expf(v1 - m), e2 = __expf(v2 - m);
  float su = e0 + e1 + e2;
#pragma unroll
  for (int o = 32; o; o >>= 1) su += __shfl_xor(su, o, 64);
  if ((tid & 63) == 0) rsum[tid >> 6] = su;
  __syncthreads();
  float inv = 1.0f / (rsum[0] + rsum[1] + rsum[2] + rsum[3]);
  p[tid]       = f2bf(e0 * inv);
  p[tid + 256] = f2bf(e1 * inv);
  p[tid + 512] = f2bf(e2 * inv);
}

extern "C" void kernel_launch(void* const* d_in, const int* in_sizes, int n_in,
                              void* d_out, int out_size, void* d_ws, size_t ws_size,
                              hipStream_t stream) {
  const float* x     = (const float*)d_in[0];
  const float* gamma = (const float*)d_in[1];
  float* out = (float*)d_out;

  // workspace layout (246 MiB of the 768 MiB ws — the R5 poison fill showed
  // ws_size = 768 MiB, so XT gets its own region instead of sharing Xb):
  //   [0, 100663296)           : Xb bf16 [16][768][4096]
  //   [100663296, +100663296)  : XT bf16 [16][4096][768]
  //   [201326592, +37748736)   : S fp32 [16][768][768]
  //   [239075328, +18874368)   : P bf16 [16][768][768]
  char* ws = (char*)d_ws;
  short* Xb = (short*)ws;
  short* XT = (short*)(ws + 100663296);
  float* S  = (float*)(ws + 201326592);
  short* P  = (short*)(ws + 239075328);

  // 1) fused: Xb = bf16(x), XT = bf16(x)^T  (reads x once)
  k_prep<<<dim3(NDIM / 64, CDIM / 64, BATCH), 256, 0, stream>>>(x, Xb, XT);
  // 2) S = Xb * Xb^T  (M=N=768, K=4096), 192^2, 3-slot pipeline: 256 blocks
  k_gemm1<<<dim3(8, 2 * 16, 1), 512, 0, stream>>>(Xb, S);
  // 3) P = softmax_rows(S), bf16
  k_softmax<<<BATCH * CDIM, 256, 0, stream>>>(S, P);
  // 4) out = gamma * (P * XT^T)  (M=768, N=4096, K=768), 256^2: 768 blocks
  k_gemm<CDIM, NDIM, CDIM, 256, 256, true>
      <<<dim3(8, 2 * 48, 1), 512, 0, stream>>>(P, XT, out, gamma);
}